// Round 1
// baseline (277.034 us; speedup 1.0000x reference)
//
#include <hip/hip_runtime.h>

#define N 24
#define D 256
#define DP 260            // padded LDS row stride (floats) to spread banks
#define BLK 256
#define INFV 1e9f

__global__ __launch_bounds__(BLK) void hungarian_fused(
    const float* __restrict__ slots,
    const float* __restrict__ prev,
    float* __restrict__ out)
{
    __shared__ float sc[N][DP];       // raw current slots
    __shared__ float sp[N][DP];       // raw prev slots
    __shared__ float cost[N][N + 2];  // cost matrix, stride 26
    __shared__ float nrm[2][N];       // [0]=prev row norms, [1]=cur row norms
    __shared__ int   s_col[N];        // col_ind[row]

    const int b   = blockIdx.x;
    const int tid = threadIdx.x;
    const int lane = tid & 63;
    const int wv   = tid >> 6;

    const float4* sb4 = (const float4*)(slots + (size_t)b * N * D);
    const float4* pb4 = (const float4*)(prev  + (size_t)b * N * D);

    // ---- 1. stage both matrices (float4, coalesced): 1536 quads each ----
    #pragma unroll
    for (int r = 0; r < 6; ++r) {
        int idx = r * BLK + tid;          // 0..1535
        int i = idx >> 6;                 // row
        int q = idx & 63;                 // quad within row
        float4 a = sb4[idx];
        float4 c = pb4[idx];
        *(float4*)&sc[i][q * 4] = a;
        *(float4*)&sp[i][q * 4] = c;
    }
    __syncthreads();

    // ---- 2. row norms: wave wv handles rows wv, wv+4, ... ----
    for (int i = wv; i < N; i += 4) {
        float xp0 = sp[i][lane],       xp1 = sp[i][lane + 64];
        float xp2 = sp[i][lane + 128], xp3 = sp[i][lane + 192];
        float sP = xp0*xp0 + xp1*xp1 + xp2*xp2 + xp3*xp3;
        float xc0 = sc[i][lane],       xc1 = sc[i][lane + 64];
        float xc2 = sc[i][lane + 128], xc3 = sc[i][lane + 192];
        float sC = xc0*xc0 + xc1*xc1 + xc2*xc2 + xc3*xc3;
        #pragma unroll
        for (int off = 32; off >= 1; off >>= 1) {
            sP += __shfl_xor(sP, off);
            sC += __shfl_xor(sC, off);
        }
        if (lane == 0) {
            nrm[0][i] = fmaxf(sqrtf(sP), 1e-12f);
            nrm[1][i] = fmaxf(sqrtf(sC), 1e-12f);
        }
    }
    __syncthreads();

    // ---- 3. cost[i][j] = 1 - <p_i, c_j>/(|p_i||c_j|), 2x2 register tiles ----
    if (tid < 144) {
        int ti = (tid / 12) * 2;
        int tj = (tid % 12) * 2;
        const float4* p0 = (const float4*)&sp[ti][0];
        const float4* p1 = (const float4*)&sp[ti + 1][0];
        const float4* c0 = (const float4*)&sc[tj][0];
        const float4* c1 = (const float4*)&sc[tj + 1][0];
        float a00 = 0.f, a01 = 0.f, a10 = 0.f, a11 = 0.f;
        int q0 = tid & 63;
        #pragma unroll 4
        for (int k = 0; k < 64; ++k) {
            int q = (q0 + k) & 63;
            float4 x0 = p0[q], x1 = p1[q], y0 = c0[q], y1 = c1[q];
            a00 += x0.x*y0.x + x0.y*y0.y + x0.z*y0.z + x0.w*y0.w;
            a01 += x0.x*y1.x + x0.y*y1.y + x0.z*y1.z + x0.w*y1.w;
            a10 += x1.x*y0.x + x1.y*y0.y + x1.z*y0.z + x1.w*y0.w;
            a11 += x1.x*y1.x + x1.y*y1.y + x1.z*y1.z + x1.w*y1.w;
        }
        float rp0 = nrm[0][ti], rp1 = nrm[0][ti + 1];
        float rc0 = nrm[1][tj], rc1 = nrm[1][tj + 1];
        cost[ti][tj]         = 1.0f - a00 / (rp0 * rc0);
        cost[ti][tj + 1]     = 1.0f - a01 / (rp0 * rc1);
        cost[ti + 1][tj]     = 1.0f - a10 / (rp1 * rc0);
        cost[ti + 1][tj + 1] = 1.0f - a11 / (rp1 * rc1);
    }
    __syncthreads();

    // ---- 4. Hungarian (JV shortest augmenting path) on wave 0 ----
    // lane j (< N+1) owns column j's state in registers; cross-lane via shfl.
    if (tid < 64) {
        float u = 0.f;     // lane < N : row potential of row `lane`
        float v = 0.f;     // lane <= N: col potential
        int   p = -1;      // lane <= N: row assigned to col `lane`

        for (int i = 0; i < N; ++i) {
            if (lane == N) p = i;            // virtual start col holds row i
            float minv = INFV;
            int   way  = 0;
            bool  used = false;
            bool  rowInTree = false;         // lane < N: row `lane` in tree
            int   j0 = N;

            while (true) {
                used = used || (lane == j0);
                int   i0   = __shfl(p, j0);          // row assigned to j0
                rowInTree  = rowInTree || (lane == i0);
                float u_i0 = __shfl(u, i0);
                int   jc   = (lane < N) ? lane : 0;
                float cur  = cost[i0][jc] - u_i0 - v;
                bool  active = (lane < N) && !used;
                if (active && cur < minv) { minv = cur; way = j0; }
                float masked = active ? minv : INFV;

                // packed argmin: monotonic uint key, low 6 bits = lane
                unsigned k = __float_as_uint(masked);
                k = k ^ ((unsigned)(((int)k) >> 31) | 0x80000000u);
                k = (k & 0xFFFFFFC0u) | (unsigned)lane;
                #pragma unroll
                for (int off = 32; off >= 1; off >>= 1) {
                    unsigned o = __shfl_xor(k, off);
                    k = (o < k) ? o : k;
                }
                int   j1    = (int)(k & 63u);
                float delta = __shfl(masked, j1);

                if (lane < N && rowInTree) u += delta;
                if (lane <= N) {
                    if (used) v -= delta; else minv -= delta;
                }
                j0 = j1;
                int pj = __shfl(p, j0);
                if (pj < 0) break;            // reached a free column
            }

            // augment back to the virtual column
            int j = j0;
            while (j != N) {
                int jp  = __shfl(way, j);
                int pjp = __shfl(p, jp);
                if (lane == j) p = pjp;
                j = jp;
            }
        }
        if (lane < N) s_col[p] = lane;        // col_ind[row p] = col lane
    }
    __syncthreads();

    // ---- 5. gather: out[b][i][:] = slots[b][col[i]][:], from LDS ----
    float4* ob4 = (float4*)(out + (size_t)b * N * D);
    #pragma unroll
    for (int r = 0; r < 6; ++r) {
        int idx = r * BLK + tid;
        int i = idx >> 6;
        int q = idx & 63;
        int c = s_col[i];
        ob4[idx] = *(const float4*)&sc[c][q * 4];
    }
}

extern "C" void kernel_launch(void* const* d_in, const int* in_sizes, int n_in,
                              void* d_out, int out_size, void* d_ws, size_t ws_size,
                              hipStream_t stream) {
    const float* slots = (const float*)d_in[0];
    const float* prev  = (const float*)d_in[1];
    float* out = (float*)d_out;
    int B = in_sizes[0] / (N * D);
    hungarian_fused<<<B, BLK, 0, stream>>>(slots, prev, out);
}

// Round 2
// 209.557 us; speedup vs baseline: 1.3220x; 1.3220x over previous
//
#include <hip/hip_runtime.h>

#define N 24
#define D 256
#define DP 260            // padded LDS row stride (floats) for staging
#define CP 26             // cost row stride
#define BLK 256
#define NB 4              // batches per block, one per wave in phase B
#define INFV 1e9f

__global__ __launch_bounds__(BLK) void hungarian_fused(
    const float* __restrict__ slots,
    const float* __restrict__ prev,
    float* __restrict__ out, int B)
{
    __shared__ float sp[N][DP];          // prev rows (staged, reused per m)
    __shared__ float sc[N][DP];          // cur rows
    __shared__ float cost[NB][N][CP];    // 4 cost matrices
    __shared__ float inrm[2][N];         // reciprocal norms: [0]=prev,[1]=cur
    __shared__ int   colw[NB][N];        // col_ind[row] per batch

    const int tid  = threadIdx.x;
    const int lane = tid & 63;
    const int wv   = tid >> 6;
    const int b0   = blockIdx.x * NB;

    // ================= Phase A: stage + norms + cost GEMM, per batch =======
    for (int m = 0; m < NB; ++m) {
        int b = b0 + m;
        if (b < B) {
            const float4* sb4 = (const float4*)(slots + (size_t)b * N * D);
            const float4* pb4 = (const float4*)(prev  + (size_t)b * N * D);
            // wave wv stages rows wv, wv+4, ..., wv+20; lane = quad index.
            // Fold row-norm reduction into the staging pass.
            #pragma unroll
            for (int r = 0; r < 6; ++r) {
                int i = r * 4 + wv;
                float4 a = sb4[i * 64 + lane];
                float4 c = pb4[i * 64 + lane];
                *(float4*)&sc[i][lane * 4] = a;
                *(float4*)&sp[i][lane * 4] = c;
                float sa = a.x*a.x + a.y*a.y + a.z*a.z + a.w*a.w;
                float sb = c.x*c.x + c.y*c.y + c.z*c.z + c.w*c.w;
                #pragma unroll
                for (int off = 32; off >= 1; off >>= 1) {
                    sa += __shfl_xor(sa, off);
                    sb += __shfl_xor(sb, off);
                }
                if (lane == 0) {
                    inrm[1][i] = 1.0f / fmaxf(sqrtf(sa), 1e-12f);
                    inrm[0][i] = 1.0f / fmaxf(sqrtf(sb), 1e-12f);
                }
            }
        }
        __syncthreads();
        if (b < B && tid < 144) {
            // 2x2 register-tiled fp32 GEMM: cost = 1 - <p_i,c_j>*irp_i*irc_j
            int ti = (tid / 12) * 2;
            int tj = (tid % 12) * 2;
            const float4* p0 = (const float4*)&sp[ti][0];
            const float4* p1 = (const float4*)&sp[ti + 1][0];
            const float4* c0 = (const float4*)&sc[tj][0];
            const float4* c1 = (const float4*)&sc[tj + 1][0];
            float a00 = 0.f, a01 = 0.f, a10 = 0.f, a11 = 0.f;
            int q0 = tid & 63;
            #pragma unroll 4
            for (int k = 0; k < 64; ++k) {
                int q = (q0 + k) & 63;
                float4 x0 = p0[q], x1 = p1[q], y0 = c0[q], y1 = c1[q];
                a00 += x0.x*y0.x + x0.y*y0.y + x0.z*y0.z + x0.w*y0.w;
                a01 += x0.x*y1.x + x0.y*y1.y + x0.z*y1.z + x0.w*y1.w;
                a10 += x1.x*y0.x + x1.y*y0.y + x1.z*y0.z + x1.w*y0.w;
                a11 += x1.x*y1.x + x1.y*y1.y + x1.z*y1.z + x1.w*y1.w;
            }
            float rp0 = inrm[0][ti], rp1 = inrm[0][ti + 1];
            float rc0 = inrm[1][tj], rc1 = inrm[1][tj + 1];
            cost[m][ti][tj]         = 1.0f - a00 * (rp0 * rc0);
            cost[m][ti][tj + 1]     = 1.0f - a01 * (rp0 * rc1);
            cost[m][ti + 1][tj]     = 1.0f - a10 * (rp1 * rc0);
            cost[m][ti + 1][tj + 1] = 1.0f - a11 * (rp1 * rc1);
        }
        __syncthreads();   // before next m overwrites sp/sc
    }

    // ================= Phase B: one Hungarian per wave (no syncs) ==========
    // Lanes 0..24 of each 32-half own column state; upper half mirrors the
    // lower half exactly so control flow stays wave-uniform. Width-32
    // shuffles keep the halves independent (and identical).
    const int bw = b0 + wv;
    if (bw < B) {
        const int   jl = lane & 31;           // mirrored column id
        const float* C = &cost[wv][0][0];     // stride CP
        float u = 0.f;                        // jl<N: row potential
        float v = 0.f;                        // jl<=N: col potential
        int   p = -1;                         // jl<=N: row assigned to col jl
        const int jc = (jl < N) ? jl : 0;

        for (int i = 0; i < N; ++i) {
            if (jl == N) p = i;
            float minv = INFV;
            int   way  = 0;
            bool  used = false;
            bool  rowInTree = false;
            int   j0 = N;
            int   i0 = i;                     // row assigned to j0

            while (true) {
                used       = used       || (jl == j0);
                rowInTree  = rowInTree  || (jl == i0);
                float u_i0 = __shfl(u, i0, 32);
                float cur  = C[i0 * CP + jc] - u_i0 - v;
                bool  active = (jl < N) && !used;
                if (active && cur < minv) { minv = cur; way = j0; }
                float masked = active ? minv : INFV;

                // packed argmin over the 32-half: monotone uint key, low5=lane
                unsigned k = __float_as_uint(masked);
                k = k ^ ((unsigned)(((int)k) >> 31) | 0x80000000u);
                k = (k & 0xFFFFFFE0u) | (unsigned)jl;
                #pragma unroll
                for (int off = 16; off >= 1; off >>= 1) {
                    unsigned o = __shfl_xor(k, off, 32);
                    k = (o < k) ? o : k;
                }
                int   j1    = (int)(k & 31u);
                float delta = __shfl(masked, j1, 32);

                if (jl < N && rowInTree) u += delta;
                if (jl <= N) {
                    if (used) v -= delta; else minv -= delta;
                }
                j0 = j1;
                i0 = __shfl(p, j0, 32);
                if (i0 < 0) break;            // free column reached
            }

            // augment back to the virtual column
            int j = j0;
            while (j != N) {
                int jp  = __shfl(way, j, 32);
                int pjp = __shfl(p, jp, 32);
                if (jl == j) p = pjp;
                j = jp;
            }
        }
        if (lane < 32 && jl < N) colw[wv][p] = jl;  // col_ind[row p] = jl
    }

    // ================= Phase C: gather from global (cache-warm) ============
    if (bw < B) {
        const float4* sg4 = (const float4*)(slots + (size_t)bw * N * D);
        float4*       og4 = (float4*)(out + (size_t)bw * N * D);
        #pragma unroll
        for (int i = 0; i < N; ++i) {
            int c = colw[wv][i];
            og4[i * 64 + lane] = sg4[c * 64 + lane];
        }
    }
}

extern "C" void kernel_launch(void* const* d_in, const int* in_sizes, int n_in,
                              void* d_out, int out_size, void* d_ws, size_t ws_size,
                              hipStream_t stream) {
    const float* slots = (const float*)d_in[0];
    const float* prev  = (const float*)d_in[1];
    float* out = (float*)d_out;
    int B = in_sizes[0] / (N * D);
    int grid = (B + NB - 1) / NB;
    hungarian_fused<<<grid, BLK, 0, stream>>>(slots, prev, out, B);
}

// Round 3
// 194.531 us; speedup vs baseline: 1.4241x; 1.0772x over previous
//
#include <hip/hip_runtime.h>
#include <math.h>

#define N    24
#define D    256
#define BLK  256
#define NB   4            // batches per block = waves per block
#define CTS  28           // costT row stride (floats), 16B-aligned
#define INFV 1e9f

__device__ __forceinline__ int readlane_i(int x, int l) {
    return __builtin_amdgcn_readlane(x, l);
}
__device__ __forceinline__ float readlane_f(float x, int l) {
    return __uint_as_float((unsigned)__builtin_amdgcn_readlane((int)__float_as_uint(x), l));
}

// unsigned-min reduce over lanes 0..31 (lanes 32..63 must hold large keys);
// result valid in lane 31. Pure DPP/VALU — no DS pipe.
__device__ __forceinline__ unsigned wave_min32(unsigned x) {
    unsigned t;
    t = (unsigned)__builtin_amdgcn_update_dpp((int)x, (int)x, 0xB1,  0xF, 0xF, false); x = t < x ? t : x; // quad_perm [1,0,3,2]
    t = (unsigned)__builtin_amdgcn_update_dpp((int)x, (int)x, 0x4E,  0xF, 0xF, false); x = t < x ? t : x; // quad_perm [2,3,0,1]
    t = (unsigned)__builtin_amdgcn_update_dpp((int)x, (int)x, 0x114, 0xF, 0xF, false); x = t < x ? t : x; // row_shr:4
    t = (unsigned)__builtin_amdgcn_update_dpp((int)x, (int)x, 0x118, 0xF, 0xF, false); x = t < x ? t : x; // row_shr:8  -> lane15 = row min
    t = (unsigned)__builtin_amdgcn_update_dpp((int)x, (int)x, 0x142, 0xF, 0xF, false); x = t < x ? t : x; // row_bcast:15 -> lane31 = min(0..31)
    return x;
}

#define DOT4(a, b) ((a).x*(b).x + (a).y*(b).y + (a).z*(b).z + (a).w*(b).w)
#define LGKM0() __asm__ volatile("s_waitcnt lgkmcnt(0)" ::: "memory")

__global__ __launch_bounds__(BLK) void hungarian_fused(
    const float* __restrict__ slots,
    const float* __restrict__ prev,
    float* __restrict__ out, int B)
{
    __shared__ __align__(16) float costT[NB][N][CTS]; // [wave][col][row]
    __shared__ int winner[NB][N];                     // col claiming row r
    __shared__ int colw[NB][N];                       // col_ind[row]

    const int tid  = threadIdx.x;
    const int lane = tid & 63;
    const int wv   = tid >> 6;
    const int bw   = blockIdx.x * NB + wv;
    if (bw >= B) return;

    // ============ Phase A: per-wave cost GEMM straight from global =========
    // 8x8 lane grid, 3x3 register tile per lane. Lanes sharing rg read
    // identical prev addresses (HW-coalesced broadcast); same for cg/slots.
    const int rg = lane >> 3;       // prev rows 3rg..3rg+2
    const int cg = lane & 7;        // cur  rows 3cg..3cg+2
    const float4* pA = (const float4*)(prev  + (size_t)bw * N * D) + rg * 3 * (D / 4);
    const float4* pC = (const float4*)(slots + (size_t)bw * N * D) + cg * 3 * (D / 4);

    float s00=0,s01=0,s02=0,s10=0,s11=0,s12=0,s20=0,s21=0,s22=0;
    float pa0=0,pa1=0,pa2=0,pc0=0,pc1=0,pc2=0;
    #pragma unroll 2
    for (int k = 0; k < 64; ++k) {
        float4 a0 = pA[k], a1 = pA[64+k], a2 = pA[128+k];
        float4 b0 = pC[k], b1 = pC[64+k], b2 = pC[128+k];
        s00 += DOT4(a0,b0); s01 += DOT4(a0,b1); s02 += DOT4(a0,b2);
        s10 += DOT4(a1,b0); s11 += DOT4(a1,b1); s12 += DOT4(a1,b2);
        s20 += DOT4(a2,b0); s21 += DOT4(a2,b1); s22 += DOT4(a2,b2);
        pa0 += DOT4(a0,a0); pa1 += DOT4(a1,a1); pa2 += DOT4(a2,a2);
        pc0 += DOT4(b0,b0); pc1 += DOT4(b1,b1); pc2 += DOT4(b2,b2);
    }
    float ira0 = 1.0f / fmaxf(sqrtf(pa0), 1e-12f);
    float ira1 = 1.0f / fmaxf(sqrtf(pa1), 1e-12f);
    float ira2 = 1.0f / fmaxf(sqrtf(pa2), 1e-12f);
    float irc0 = 1.0f / fmaxf(sqrtf(pc0), 1e-12f);
    float irc1 = 1.0f / fmaxf(sqrtf(pc1), 1e-12f);
    float irc2 = 1.0f / fmaxf(sqrtf(pc2), 1e-12f);

    {   // costT[col][row] = 1 - <prev_row, cur_col> * ira * irc
        float* ct = &costT[wv][0][0];
        const int cb = cg * 3, rb = rg * 3;
        ct[(cb+0)*CTS + rb+0] = 1.0f - s00*ira0*irc0;
        ct[(cb+1)*CTS + rb+0] = 1.0f - s01*ira0*irc1;
        ct[(cb+2)*CTS + rb+0] = 1.0f - s02*ira0*irc2;
        ct[(cb+0)*CTS + rb+1] = 1.0f - s10*ira1*irc0;
        ct[(cb+1)*CTS + rb+1] = 1.0f - s11*ira1*irc1;
        ct[(cb+2)*CTS + rb+1] = 1.0f - s12*ira1*irc2;
        ct[(cb+0)*CTS + rb+2] = 1.0f - s20*ira2*irc0;
        ct[(cb+1)*CTS + rb+2] = 1.0f - s21*ira2*irc1;
        ct[(cb+2)*CTS + rb+2] = 1.0f - s22*ira2*irc2;
    }
    LGKM0();   // order ds_write -> ds_read within this wave

    // ============ Phase B: DS-free Hungarian (JV SAP), one wave/batch ======
    const bool isCol = (lane < N);
    const int  jj    = isCol ? lane : 0;
    float cq[24];                         // lane j holds column j, rows 0..23
    {
        const float4* cp4 = (const float4*)&costT[wv][jj][0];
        #pragma unroll
        for (int r = 0; r < 6; ++r) {
            float4 q = cp4[r];
            cq[r*4+0] = q.x; cq[r*4+1] = q.y; cq[r*4+2] = q.z; cq[r*4+3] = q.w;
        }
    }

    // ---- column reduction warm start: v[j] = min_i C[i][j] ----
    float cm = cq[0]; int ri = 0;
    #pragma unroll
    for (int i = 1; i < N; ++i) { if (cq[i] < cm) { cm = cq[i]; ri = i; } }

    if (isCol) winner[wv][lane] = -1;
    LGKM0();
    if (isCol) winner[wv][ri] = lane;     // races resolve to one winner
    LGKM0();
    int p = -1;                           // row assigned to col `lane`
    if (isCol && winner[wv][ri] == lane) p = ri;
    const int widx = isCol ? lane : 0;
    unsigned long long mm = __ballot(isCol && winner[wv][widx] >= 0);
    unsigned freeRows = (~(unsigned)mm) & ((1u << N) - 1);

    float uu  = 0.0f;                     // lane r: row potential u[r]
    float v   = isCol ? cm : INFV;        // lane j: col potential v[j]
    int   way = -1;                       // lane j: parent col on path

    while (freeRows) {
        const int f = (int)__builtin_ctz(freeRows);
        freeRows &= freeRows - 1;

        float minv  = INFV;
        bool  used  = false;
        bool  inTree = false;
        int   s_j0 = -1;                  // virtual column
        int   s_i0 = f;
        float s_u0 = readlane_f(uu, f);
        int   j1   = 0;

        while (true) {
            inTree = inTree || (lane == s_i0);
            used   = used   || (lane == s_j0);

            float cij;                    // C[s_i0][lane] — uniform select
            switch (s_i0) {
                case 0:  cij = cq[0];  break;  case 1:  cij = cq[1];  break;
                case 2:  cij = cq[2];  break;  case 3:  cij = cq[3];  break;
                case 4:  cij = cq[4];  break;  case 5:  cij = cq[5];  break;
                case 6:  cij = cq[6];  break;  case 7:  cij = cq[7];  break;
                case 8:  cij = cq[8];  break;  case 9:  cij = cq[9];  break;
                case 10: cij = cq[10]; break;  case 11: cij = cq[11]; break;
                case 12: cij = cq[12]; break;  case 13: cij = cq[13]; break;
                case 14: cij = cq[14]; break;  case 15: cij = cq[15]; break;
                case 16: cij = cq[16]; break;  case 17: cij = cq[17]; break;
                case 18: cij = cq[18]; break;  case 19: cij = cq[19]; break;
                case 20: cij = cq[20]; break;  case 21: cij = cq[21]; break;
                case 22: cij = cq[22]; break;  default: cij = cq[23]; break;
            }
            float cur = cij - s_u0 - v;
            bool  act = isCol && !used;
            if (act && cur < minv) { minv = cur; way = s_j0; }
            float masked = act ? minv : INFV;

            // packed argmin via DPP: monotone uint key, low 6 bits = lane
            unsigned key = __float_as_uint(masked);
            key ^= (unsigned)((int)key >> 31) | 0x80000000u;
            key  = (key & 0xFFFFFFC0u) | (unsigned)lane;
            unsigned kmin = (unsigned)readlane_i((int)wave_min32(key), 31);
            j1 = (int)(kmin & 63u);

            float delta = readlane_f(masked, j1);
            int   i0n   = readlane_i(p, j1);
            float u0n   = readlane_f(uu, i0n & 31);   // safe dummy if i0n<0

            if (inTree) uu += delta;                  // rows in tree (incl f)
            if (used) v -= delta;
            else if (act) minv -= delta;

            if (i0n < 0) break;                       // free column reached
            s_j0 = j1; s_i0 = i0n; s_u0 = u0n;
        }

        // augment back to the virtual column
        int jcur = j1;
        while (true) {
            int wj   = readlane_i(way, jcur);
            int pnew = (wj < 0) ? f : readlane_i(p, wj);
            if (lane == jcur) p = pnew;
            if (wj < 0) break;
            jcur = wj;
        }
    }

    if (isCol) colw[wv][p] = lane;        // col_ind[row p] = col `lane`
    LGKM0();

    // ============ Phase C: gather out[i][:] = slots[col[i]][:] =============
    const float4* sg4 = (const float4*)(slots + (size_t)bw * N * D);
    float4*       og4 = (float4*)(out + (size_t)bw * N * D);
    #pragma unroll
    for (int i = 0; i < N; ++i) {
        int c = colw[wv][i];
        og4[i * 64 + lane] = sg4[c * 64 + lane];
    }
}

extern "C" void kernel_launch(void* const* d_in, const int* in_sizes, int n_in,
                              void* d_out, int out_size, void* d_ws, size_t ws_size,
                              hipStream_t stream) {
    const float* slots = (const float*)d_in[0];
    const float* prev  = (const float*)d_in[1];
    float* out = (float*)d_out;
    int B = in_sizes[0] / (N * D);
    int grid = (B + NB - 1) / NB;
    hungarian_fused<<<grid, BLK, 0, stream>>>(slots, prev, out, B);
}